// Round 3
// baseline (365.312 us; speedup 1.0000x reference)
//
#include <hip/hip_runtime.h>
#include <hip/hip_bf16.h>

typedef unsigned short u16;
using bf16x8 = __bf16 __attribute__((ext_vector_type(8)));
using f32x4  = float  __attribute__((ext_vector_type(4)));

#define BB 4
#define TT 4096
#define DD 1024
#define MROWS (BB*TT)   /* 16384 */
#define CT 32           /* scan chunk length */
#define NC (TT/CT)      /* 128 chunks */

__device__ __forceinline__ float sigm(float x) { return 1.0f / (1.0f + __expf(-x)); }
__device__ __forceinline__ u16 f2bf(float f) {
    __hip_bfloat16 h = __float2bfloat16(f);
    return *reinterpret_cast<u16*>(&h);
}
__device__ __forceinline__ float bf2f(u16 u) { return __uint_as_float(((unsigned)u) << 16); }

// async 16B global->LDS (direct-to-shared DMA; LDS dest must be wave-uniform base + lane*16)
__device__ __forceinline__ void async_cp16(const u16* g, u16* l) {
    __builtin_amdgcn_global_load_lds(
        (const __attribute__((address_space(1))) unsigned int*)g,
        (__attribute__((address_space(3))) unsigned int*)l, 16, 0, 0);
}

// ---------------------------------------------------------------- prep: fp32->bf16
// converts x (4,194,304 float4) then the 4 weights (1,048,576 float4) in one kernel
__global__ __launch_bounds__(256) void prep_kernel(const float* __restrict__ x,
                                                   const float* __restrict__ w0,
                                                   const float* __restrict__ w1,
                                                   const float* __restrict__ w2,
                                                   const float* __restrict__ w3,
                                                   u16* __restrict__ xo,
                                                   u16* __restrict__ Wb) {
    const int i = blockIdx.x * 256 + threadIdx.x;
    const float* s;
    u16* d;
    if (i < 4194304) {
        s = x + (size_t)i * 4;
        d = xo + (size_t)i * 4;
    } else {
        const int j = i - 4194304;
        const int sel = j >> 18;
        const int off = j & 262143;
        const float* w = (sel == 0) ? w0 : (sel == 1) ? w1 : (sel == 2) ? w2 : w3;
        s = w + (size_t)off * 4;
        d = Wb + ((size_t)sel << 20) + (size_t)off * 4;
    }
    float4 v = *(const float4*)s;
    ushort4 u;
    u.x = f2bf(v.x); u.y = f2bf(v.y); u.z = f2bf(v.z); u.w = f2bf(v.w);
    *(ushort4*)d = u;
}

// ---------------------------------------------------------------- GEMM
// C[m][n] = sum_k A[m][k] * W[n][k], A:[M,K] bf16 row-major, W:[N,K] bf16 row-major.
// 128x128 tile, BK=64, 4 waves (2x2), each wave 64x64 via 4x4 mfma_f32_16x16x32_bf16.
// XOR-swizzle on the GLOBAL address side; LDS dest stays contiguous for
// global_load_lds. R0/R1: SQ_LDS_BANK_CONFLICT == 0.
#define BM 128
#define BN 128
#define BK 64

template <typename OutT>
__global__ __launch_bounds__(256, 4)
void gemm_bf16_bt(const u16* __restrict__ Ag, const u16* __restrict__ Bg, int K,
                  OutT* __restrict__ P0, OutT* __restrict__ P1, OutT* __restrict__ P2) {
    __shared__ u16 As[BM * BK];
    __shared__ u16 Bs[BN * BK];

    const int tid  = threadIdx.x;
    const int lane = tid & 63;
    const int wid  = tid >> 6;
    const int wm   = wid >> 1;
    const int wn   = wid & 1;
    const int lr   = lane & 15;
    const int lq   = lane >> 4;

    const long bM  = (long)blockIdx.y * BM;
    const long bN0 = (long)blockIdx.x * BN;

    const f32x4 zero = {0.f, 0.f, 0.f, 0.f};
    f32x4 acc[4][4];
#pragma unroll
    for (int i = 0; i < 4; i++)
#pragma unroll
        for (int j = 0; j < 4; j++) acc[i][j] = zero;

    for (int kt = 0; kt < K; kt += BK) {
        __syncthreads();
#pragma unroll
        for (int j = 0; j < 4; j++) {
            const int G  = j * 256 + tid;     // LDS granule = wave_base + lane (contiguous)
            const int m  = G >> 3;
            const int p  = G & 7;
            const int gk = p ^ (m & 7);       // swizzle applied to global k-granule
            async_cp16(Ag + (bM + m) * K + kt + gk * 8, &As[G * 8]);
            async_cp16(Bg + (bN0 + m) * K + kt + gk * 8, &Bs[G * 8]);
        }
        __syncthreads();
#pragma unroll
        for (int kk = 0; kk < BK / 32; kk++) {
            bf16x8 av[4], bv[4];
#pragma unroll
            for (int f = 0; f < 4; f++) {
                const int am = wm * 64 + f * 16 + lr;
                const int ag = (kk * 4 + lq) ^ (am & 7);
                av[f] = *(const bf16x8*)(&As[am * 64 + ag * 8]);
                const int bn = wn * 64 + f * 16 + lr;
                const int bg = (kk * 4 + lq) ^ (bn & 7);
                bv[f] = *(const bf16x8*)(&Bs[bn * 64 + bg * 8]);
            }
#pragma unroll
            for (int i = 0; i < 4; i++)
#pragma unroll
                for (int j = 0; j < 4; j++)
                    acc[i][j] = __builtin_amdgcn_mfma_f32_16x16x32_bf16(av[i], bv[j],
                                                                        acc[i][j], 0, 0, 0);
        }
    }

    const int pl = (int)(bN0 >> 10);
    OutT* P = (pl == 0) ? P0 : ((pl == 1) ? P1 : P2);
    const int cn = (int)(bN0 & 1023);
#pragma unroll
    for (int i = 0; i < 4; i++) {
        const long m0 = bM + wm * 64 + i * 16 + lq * 4;
#pragma unroll
        for (int j = 0; j < 4; j++) {
            const int n = cn + wn * 64 + j * 16 + lr;
#pragma unroll
            for (int r = 0; r < 4; r++) {
                if constexpr (sizeof(OutT) == 2)
                    P[(m0 + r) * 1024 + n] = f2bf(acc[i][j][r]);
                else
                    P[(m0 + r) * 1024 + n] = acc[i][j][r];
            }
        }
    }
}

// ---------------------------------------------------------------- chunked scan
// h_t = f_t * h_{t-1} + silu(i_t)*(1-f_t),  f = sigmoid(f_pre); planes bf16.
// pass1: per-chunk (F = prod f, I = local scan tail); 4 d-lanes per thread.
__global__ __launch_bounds__(256) void scan_pass1(const u16* __restrict__ ip,
                                                  const u16* __restrict__ fp,
                                                  float* __restrict__ Fc,
                                                  float* __restrict__ Ic) {
    const int q  = blockIdx.x * 256 + threadIdx.x;  // B*NC*D/4 threads
    const int d4 = q & 255;
    const int c  = (q >> 8) & (NC - 1);
    const int b  = q >> 15;
    size_t base = ((size_t)(b * TT + c * CT) << 10) + d4 * 4;
    float4 F = {1.f, 1.f, 1.f, 1.f};
    float4 I = {0.f, 0.f, 0.f, 0.f};
#pragma unroll 4
    for (int t = 0; t < CT; t++) {
        ushort4 fu = *(const ushort4*)(fp + base);
        ushort4 iu = *(const ushort4*)(ip + base);
        base += DD;
        float f0 = sigm(bf2f(fu.x)), f1 = sigm(bf2f(fu.y)),
              f2 = sigm(bf2f(fu.z)), f3 = sigm(bf2f(fu.w));
        float i0 = bf2f(iu.x), i1 = bf2f(iu.y), i2 = bf2f(iu.z), i3 = bf2f(iu.w);
        I.x = fmaf(f0, I.x, i0 * sigm(i0) * (1.f - f0));
        I.y = fmaf(f1, I.y, i1 * sigm(i1) * (1.f - f1));
        I.z = fmaf(f2, I.z, i2 * sigm(i2) * (1.f - f2));
        I.w = fmaf(f3, I.w, i3 * sigm(i3) * (1.f - f3));
        F.x *= f0; F.y *= f1; F.z *= f2; F.w *= f3;
    }
    const size_t o = ((size_t)((b * NC + c) << 10)) + d4 * 4;
    *(float4*)(Fc + o) = F;
    *(float4*)(Ic + o) = I;
}

// pass2: carry across chunks (B*D/4 threads)
__global__ __launch_bounds__(256) void scan_pass2(const float* __restrict__ Fc,
                                                  const float* __restrict__ Ic,
                                                  float* __restrict__ Hin) {
    const int q  = blockIdx.x * 256 + threadIdx.x;
    const int d4 = q & 255;
    const int b  = q >> 8;
    float4 H = {0.f, 0.f, 0.f, 0.f};
    for (int c = 0; c < NC; c++) {
        const size_t idx = ((size_t)((b * NC + c) << 10)) + d4 * 4;
        float4 F = *(const float4*)(Fc + idx);
        float4 I = *(const float4*)(Ic + idx);
        *(float4*)(Hin + idx) = H;
        H.x = fmaf(F.x, H.x, I.x);
        H.y = fmaf(F.y, H.y, I.y);
        H.z = fmaf(F.z, H.z, I.z);
        H.w = fmaf(F.w, H.w, I.w);
    }
}

// finalize: recompute h within chunk, per-timestep RMSNorm over the 1024-wide row
// (block = one (b, chunk), 1024 threads = one d each), apply norm_w * swish(g),
// write o (bf16). Replaces pass3 + rmsnorm: saves the 64MB h round-trip.
__global__ __launch_bounds__(1024) void scan_finalize(const u16* __restrict__ ip,
                                                      const u16* __restrict__ fp,
                                                      const float* __restrict__ Hin,
                                                      const u16* __restrict__ g,
                                                      const float* __restrict__ w,
                                                      u16* __restrict__ oout) {
    const int t  = threadIdx.x;          // d index
    const int c  = blockIdx.x & (NC - 1);
    const int b  = blockIdx.x >> 7;
    const int lane = t & 63;
    const int wid  = t >> 6;             // 0..15
    __shared__ float red[2][16];

    size_t base = ((size_t)(b * TT + c * CT) << 10) + t;
    float h = Hin[((size_t)((b * NC + c) << 10)) + t];
    const float wn = w[t];

    for (int tt = 0; tt < CT; tt++) {
        const float fv = bf2f(fp[base]);
        const float iv = bf2f(ip[base]);
        const float gv = bf2f(g[base]);
        const float f = sigm(fv);
        h = fmaf(f, h, iv * sigm(iv) * (1.f - f));
        // block-wide sum of h^2 (1024 values)
        float ss = h * h;
#pragma unroll
        for (int o = 32; o > 0; o >>= 1) ss += __shfl_down(ss, o);
        const int pb = tt & 1;
        if (lane == 0) red[pb][wid] = ss;
        __syncthreads();
        float tot = 0.f;
#pragma unroll
        for (int k = 0; k < 16; k++) tot += red[pb][k];
        const float rms = rsqrtf(tot * (1.f / 1024.f) + 1e-5f);
        oout[base] = f2bf(h * rms * wn * gv * sigm(gv));
        base += DD;
    }
}

// ---------------------------------------------------------------- launch
extern "C" void kernel_launch(void* const* d_in, const int* in_sizes, int n_in,
                              void* d_out, int out_size, void* d_ws, size_t ws_size,
                              hipStream_t stream) {
    const float* x  = (const float*)d_in[0];
    const float* Wi = (const float*)d_in[1];
    const float* Wf = (const float*)d_in[2];
    const float* Wg = (const float*)d_in[3];
    const float* Wo = (const float*)d_in[4];
    const float* nw = (const float*)d_in[5];
    float* out = (float*)d_out;

    const size_t MB = 1ull << 20;
    char* ws = (char*)d_ws;
    u16*   xo  = (u16*)(ws);              // 32MB: x_bf16, later o_bf16
    u16*   Wb  = (u16*)(ws + 32 * MB);    // 8MB: [Wi;Wf;Wg;Wo] bf16
    u16*   Pi  = (u16*)(ws + 40 * MB);    // 32MB: i_pre bf16
    u16*   Pf  = (u16*)(ws + 72 * MB);    // 32MB: f_pre bf16
    float* Fc  = (float*)(ws + 104 * MB); // 2MB
    float* Ic  = (float*)(ws + 106 * MB); // 2MB
    float* Hin = (float*)(ws + 108 * MB); // 2MB
    u16*   g   = (u16*)d_out;             // g plane (bf16) parked in d_out

    prep_kernel<<<20480, 256, 0, stream>>>(x, Wi, Wf, Wg, Wo, xo, Wb);
    gemm_bf16_bt<u16><<<dim3(24, 128), 256, 0, stream>>>(xo, Wb, 1024, Pi, Pf, g);
    scan_pass1<<<512, 256, 0, stream>>>(Pi, Pf, Fc, Ic);
    scan_pass2<<<4, 256, 0, stream>>>(Fc, Ic, Hin);
    scan_finalize<<<512, 1024, 0, stream>>>(Pi, Pf, Hin, g, nw, xo);
    gemm_bf16_bt<float><<<dim3(8, 128), 256, 0, stream>>>(xo, Wb + 3ull * 1024 * 1024, 1024,
                                                          out, out, out);
}